// Round 8
// baseline (488.094 us; speedup 1.0000x reference)
//
#include <hip/hip_runtime.h>

#define NN 100000
#define EE 1600000
#define D 128
#define STRIDE 64                 // csr slots per node (Poisson(16); P(deg>64)~1e-18)
#define NPART 8                   // dst-space partitions (XCD-aligned)
#define PSZ (NN / NPART)          // 12500 nodes per partition
#define BCAP 204800               // per-bucket capacity (200000 expected, +10 sigma)
#define BINCAP 512                // LDS bin capacity per bucket (390 expected, +6.6 sigma)

typedef __attribute__((ext_vector_type(8))) short bf16x8;
typedef __attribute__((ext_vector_type(4))) float f32x4;

// bf16 helpers (exact unpack; RN pack)
__device__ inline unsigned int f2bf2(float a, float b) {  // pack (a=low, b=high)
    unsigned int ua = __float_as_uint(a);
    unsigned int ub = __float_as_uint(b);
    ua = (ua + 0x7fffu + ((ua >> 16) & 1u)) >> 16;
    ub = (ub + 0x7fffu + ((ub >> 16) & 1u)) >> 16;
    return ua | (ub << 16);
}
__device__ inline unsigned short f2bf(float a) {
    unsigned int u = __float_as_uint(a);
    return (unsigned short)((u + 0x7fffu + ((u >> 16) & 1u)) >> 16);
}
__device__ inline float2 bf2f2(unsigned int u) {
    return make_float2(__uint_as_float(u << 16), __uint_as_float(u & 0xffff0000u));
}

// ---------------- graph prep ----------------

// zero cursor + bucket cursors + sentinel hs row (index NN)
__global__ void init_kernel(int* __restrict__ cursor, int* __restrict__ gcur,
                            unsigned int* __restrict__ hb) {
    int i = blockIdx.x * blockDim.x + threadIdx.x;
    if (i < NN) cursor[i] = 0;
    if (i < NPART) gcur[i] = 0;
    if (i < 64) hb[(size_t)NN * 64 + i] = 0;
}

// phase 1: bin edges by dst partition into contiguous per-partition buckets.
// LDS bins flushed with one global-cursor atomic per bin; coalesced writes.
__global__ __launch_bounds__(256) void bin_kernel(const int* __restrict__ src,
                                                  const int* __restrict__ dst,
                                                  int* __restrict__ gcur,
                                                  uint2* __restrict__ buckets) {
    __shared__ uint2 bins[NPART][BINCAP];
    __shared__ int bcnt[NPART];
    __shared__ int gbase[NPART];
    if (threadIdx.x < NPART) bcnt[threadIdx.x] = 0;
    __syncthreads();
    const int per = (EE + gridDim.x - 1) / gridDim.x;
    const int lo = blockIdx.x * per;
    const int hi = min(lo + per, EE);
    for (int i = lo + threadIdx.x; i < hi; i += 256) {
        int s = src[i], d = dst[i];
        int b = d / PSZ;
        int pos = atomicAdd(&bcnt[b], 1);
        if (pos < BINCAP) {
            bins[b][pos] = make_uint2((unsigned)s, (unsigned)d);
        } else {  // overflow fallback (astronomically rare): direct global append
            int gp = atomicAdd(&gcur[b], 1);
            buckets[(size_t)b * BCAP + gp] = make_uint2((unsigned)s, (unsigned)d);
        }
    }
    __syncthreads();
    if (threadIdx.x < NPART) {
        int c = min(bcnt[threadIdx.x], BINCAP);
        gbase[threadIdx.x] = atomicAdd(&gcur[threadIdx.x], c);
        bcnt[threadIdx.x] = c;
    }
    __syncthreads();
    for (int b = 0; b < NPART; ++b) {
        const int c = bcnt[b];
        uint2* outp = buckets + (size_t)b * BCAP + gbase[b];
        for (int i = threadIdx.x; i < c; i += 256) outp[i] = bins[b][i];
    }
}

// phase 2: partition p's bucket scattered by blockIdx%8==p blocks, in 2
// dst-sub-passes so the active 1.6 MB csr sub-region stays L2-resident.
__global__ __launch_bounds__(256) void scatter2_kernel(const uint2* __restrict__ buckets,
                                                       const int* __restrict__ gcur,
                                                       int* __restrict__ cursor,
                                                       int* __restrict__ csr) {
    const int p = blockIdx.x & (NPART - 1);
    const int bp = blockIdx.x >> 3;            // 0..255
    const int cnt = gcur[p];
    const uint2* bk = buckets + (size_t)p * BCAP;
    const int mid = p * PSZ + PSZ / 2;
#pragma unroll
    for (int sub = 0; sub < 2; ++sub) {        // locality heuristic only, no sync needed
        for (int i = bp * 256 + threadIdx.x; i < cnt; i += 256 * 256) {
            uint2 e = bk[i];
            int d = (int)e.y;
            bool in = (sub == 0) ? (d < mid) : (d >= mid);
            if (in) csr[d * STRIDE + atomicAdd(&cursor[d], 1)] = (int)e.x;
        }
    }
}

// dinv from degree (cursor) + pad each csr row to a multiple of 8 with sentinel NN
__global__ void dinv_pad_kernel(const int* __restrict__ cursor, float* __restrict__ dinv,
                                int* __restrict__ csr) {
    int i = blockIdx.x * blockDim.x + threadIdx.x;
    if (i < NN) {
        int c = cursor[i];
        dinv[i] = rsqrtf(1.0f + (float)c);  // +1 self-loop
        int e = i * STRIDE + c;
        const int end = i * STRIDE + ((c + 7) & ~7);
        for (; e < end; ++e) csr[e] = NN;   // sentinel -> zero hs row
    }
}

// W[k][n] fp32 -> Wt[n][k] bf16, all three weights in one launch (192 blocks)
__global__ void wt_build3_kernel(const float* __restrict__ W1, const float* __restrict__ W2,
                                 const float* __restrict__ W3, unsigned short* __restrict__ wt1,
                                 unsigned short* __restrict__ wt2, unsigned short* __restrict__ wt3) {
    const int which = blockIdx.x >> 6;
    const float* W = which == 0 ? W1 : (which == 1 ? W2 : W3);
    unsigned short* wt = which == 0 ? wt1 : (which == 1 ? wt2 : wt3);
    int i = (blockIdx.x & 63) * 256 + threadIdx.x;
    int n = i >> 7, k = i & 127;
    wt[n * 128 + k] = f2bf(W[k * 128 + n]);
}

// ---------------- GEMM: hs(bf16) = dinv[row] * (x @ W)  via MFMA ------------
// One wave: 16 rows x 128 cols, K=128 in 4 chunks of 32.
// Operand swap: A = Wt-frag, B = x-frag -> lane holds h[m0+(lane&15)][nt*16+q*4+reg].
// Epilogue scales by dinv[row] (pre-scaled hs for the add-only aggregation).

template <bool F32IN>
__global__ __launch_bounds__(256) void gemm_mfma_kernel(const void* __restrict__ xin,
                                                        const unsigned short* __restrict__ wt,
                                                        const float* __restrict__ dinv,
                                                        unsigned int* __restrict__ hb) {
    const int wave = blockIdx.x * 4 + (threadIdx.x >> 6);
    const int m0 = wave * 16;
    if (m0 >= NN) return;
    const int lane = threadIdx.x & 63;
    const int r = lane & 15;
    const int q = lane >> 4;
    const unsigned short* wrow = wt + (size_t)r * 128 + q * 8;
    f32x4 acc[8] = {};
#pragma unroll
    for (int kc = 0; kc < 4; ++kc) {
        bf16x8 xf;
        if (F32IN) {
            const float* xrow = (const float*)xin + (size_t)(m0 + r) * 128 + q * 8 + kc * 32;
            float4 a = *(const float4*)xrow;
            float4 b = *(const float4*)(xrow + 4);
            unsigned short tmp[8] = {f2bf(a.x), f2bf(a.y), f2bf(a.z), f2bf(a.w),
                                     f2bf(b.x), f2bf(b.y), f2bf(b.z), f2bf(b.w)};
            xf = *(const bf16x8*)tmp;
        } else {
            const unsigned short* xrow =
                (const unsigned short*)xin + (size_t)(m0 + r) * 128 + q * 8 + kc * 32;
            xf = *(const bf16x8*)xrow;
        }
#pragma unroll
        for (int nt = 0; nt < 8; ++nt) {
            bf16x8 wf = *(const bf16x8*)(wrow + (size_t)nt * 16 * 128 + kc * 32);
            acc[nt] = __builtin_amdgcn_mfma_f32_16x16x32_bf16(wf, xf, acc[nt], 0, 0, 0);
        }
    }
    const float dvr = dinv[m0 + r];
    unsigned int* hrow = hb + (size_t)(m0 + r) * 64;  // uint = 2 bf16
#pragma unroll
    for (int nt = 0; nt < 8; ++nt) {
        int n = nt * 16 + q * 4;
        *(uint2*)(hrow + (n >> 1)) =
            make_uint2(f2bf2(acc[nt][0] * dvr, acc[nt][1] * dvr),
                       f2bf2(acc[nt][2] * dvr, acc[nt][3] * dvr));
    }
}

// ---------------- aggregation: out[d] = relu( dv*(hs[d] + sum_e hs[src_e]) + b )
// 4 waves per block, one node per wave; lane j owns cols 2j,2j+1.
// csr rows padded to x8 with sentinel NN (zero hs row); 16-deep main loop for
// 16 outstanding gathers per wave, optional trailing 8-batch.

template <bool BF16OUT>
__global__ __launch_bounds__(256) void aggregate_kernel(const unsigned int* __restrict__ hb,
                                                        const int* __restrict__ csr,
                                                        const int* __restrict__ cursor,
                                                        const float* __restrict__ dinv,
                                                        const float2* __restrict__ bias2,
                                                        void* __restrict__ outp) {
    const int d = blockIdx.x * 4 + (threadIdx.x >> 6);
    const int j = threadIdx.x & 63;     // lane
    const int base = d * STRIDE;
    int e = base;
    const int end = base + ((cursor[d] + 7) & ~7);
    float2 acc = bf2f2(hb[(size_t)d * 64 + j]);   // self term: hs[d]
    for (; e + 16 <= end; e += 16) {
        int4 c0 = *(const int4*)(csr + e);
        int4 c1 = *(const int4*)(csr + e + 4);
        int4 c2 = *(const int4*)(csr + e + 8);
        int4 c3 = *(const int4*)(csr + e + 12);
        unsigned int v0 = hb[(size_t)c0.x * 64 + j];
        unsigned int v1 = hb[(size_t)c0.y * 64 + j];
        unsigned int v2 = hb[(size_t)c0.z * 64 + j];
        unsigned int v3 = hb[(size_t)c0.w * 64 + j];
        unsigned int v4 = hb[(size_t)c1.x * 64 + j];
        unsigned int v5 = hb[(size_t)c1.y * 64 + j];
        unsigned int v6 = hb[(size_t)c1.z * 64 + j];
        unsigned int v7 = hb[(size_t)c1.w * 64 + j];
        unsigned int v8 = hb[(size_t)c2.x * 64 + j];
        unsigned int v9 = hb[(size_t)c2.y * 64 + j];
        unsigned int va = hb[(size_t)c2.z * 64 + j];
        unsigned int vb = hb[(size_t)c2.w * 64 + j];
        unsigned int vc = hb[(size_t)c3.x * 64 + j];
        unsigned int vd = hb[(size_t)c3.y * 64 + j];
        unsigned int ve = hb[(size_t)c3.z * 64 + j];
        unsigned int vf = hb[(size_t)c3.w * 64 + j];
        float2 f0 = bf2f2(v0), f1 = bf2f2(v1), f2 = bf2f2(v2), f3 = bf2f2(v3);
        float2 f4 = bf2f2(v4), f5 = bf2f2(v5), f6 = bf2f2(v6), f7 = bf2f2(v7);
        float2 f8 = bf2f2(v8), f9 = bf2f2(v9), fa = bf2f2(va), fb = bf2f2(vb);
        float2 fc = bf2f2(vc), fd = bf2f2(vd), fe = bf2f2(ve), ff = bf2f2(vf);
        acc.x += ((f0.x + f1.x) + (f2.x + f3.x)) + ((f4.x + f5.x) + (f6.x + f7.x)) +
                 ((f8.x + f9.x) + (fa.x + fb.x)) + ((fc.x + fd.x) + (fe.x + ff.x));
        acc.y += ((f0.y + f1.y) + (f2.y + f3.y)) + ((f4.y + f5.y) + (f6.y + f7.y)) +
                 ((f8.y + f9.y) + (fa.y + fb.y)) + ((fc.y + fd.y) + (fe.y + ff.y));
    }
    if (e < end) {  // one trailing 8-batch
        int4 c0 = *(const int4*)(csr + e);
        int4 c1 = *(const int4*)(csr + e + 4);
        unsigned int v0 = hb[(size_t)c0.x * 64 + j];
        unsigned int v1 = hb[(size_t)c0.y * 64 + j];
        unsigned int v2 = hb[(size_t)c0.z * 64 + j];
        unsigned int v3 = hb[(size_t)c0.w * 64 + j];
        unsigned int v4 = hb[(size_t)c1.x * 64 + j];
        unsigned int v5 = hb[(size_t)c1.y * 64 + j];
        unsigned int v6 = hb[(size_t)c1.z * 64 + j];
        unsigned int v7 = hb[(size_t)c1.w * 64 + j];
        float2 f0 = bf2f2(v0), f1 = bf2f2(v1), f2 = bf2f2(v2), f3 = bf2f2(v3);
        float2 f4 = bf2f2(v4), f5 = bf2f2(v5), f6 = bf2f2(v6), f7 = bf2f2(v7);
        acc.x += ((f0.x + f1.x) + (f2.x + f3.x)) + ((f4.x + f5.x) + (f6.x + f7.x));
        acc.y += ((f0.y + f1.y) + (f2.y + f3.y)) + ((f4.y + f5.y) + (f6.y + f7.y));
    }
    const float dv = dinv[d];
    float2 bb = bias2[j];
    float ox = fmaxf(dv * acc.x + bb.x, 0.0f);
    float oy = fmaxf(dv * acc.y + bb.y, 0.0f);
    if (BF16OUT) {
        ((unsigned int*)outp)[(size_t)d * 64 + j] = f2bf2(ox, oy);
    } else {
        ((float2*)outp)[(size_t)d * 64 + j] = make_float2(ox, oy);
    }
}

// ---------------- launch ----------------

extern "C" void kernel_launch(void* const* d_in, const int* in_sizes, int n_in,
                              void* d_out, int out_size, void* d_ws, size_t ws_size,
                              hipStream_t stream) {
    const float* x0 = (const float*)d_in[0];
    const int* ei = (const int*)d_in[1];   // int32 on device (harness contract)
    const float* W1 = (const float*)d_in[2];
    const float* b1 = (const float*)d_in[3];
    const float* W2 = (const float*)d_in[4];
    const float* b2 = (const float*)d_in[5];
    const float* W3 = (const float*)d_in[6];
    const float* b3 = (const float*)d_in[7];
    float* out = (float*)d_out;

    char* ws = (char*)d_ws;
    size_t off = 0;
    auto alloc = [&](size_t bytes) -> void* {
        off = (off + 511) & ~(size_t)511;
        void* p = ws + off;
        off += bytes;
        return p;
    };
    unsigned int* hb  = (unsigned int*)alloc(((size_t)NN + 1) * 64 * 4); // 25.6 MB hs (+ zero row)
    int*   csr    = (int*)  alloc((size_t)NN * STRIDE * sizeof(int));    // 25.6 MB fixed-stride CSR
    uint2* buckets = (uint2*)alloc((size_t)NPART * BCAP * sizeof(uint2)); // 13.1 MB
    int*   cursor = (int*)  alloc((size_t)NN * sizeof(int));
    float* dinv   = (float*)alloc((size_t)NN * sizeof(float));
    int*   gcur   = (int*)  alloc(NPART * sizeof(int));
    unsigned short* wt1 = (unsigned short*)alloc(128 * 128 * 2);
    unsigned short* wt2 = (unsigned short*)alloc(128 * 128 * 2);
    unsigned short* wt3 = (unsigned short*)alloc(128 * 128 * 2);

    // bf16 activation ping buffer for layers 1-2 lives in d_out's first 25.6 MB
    unsigned int* xact = (unsigned int*)d_out;

    const int* src = ei;        // edge_index[0]
    const int* dst = ei + EE;   // edge_index[1]

    // graph prep (redone every call: ws is re-poisoned)
    init_kernel<<<(NN + 255) / 256, 256, 0, stream>>>(cursor, gcur, hb);
    bin_kernel<<<512, 256, 0, stream>>>(src, dst, gcur, buckets);
    scatter2_kernel<<<2048, 256, 0, stream>>>(buckets, gcur, cursor, csr);
    dinv_pad_kernel<<<(NN + 255) / 256, 256, 0, stream>>>(cursor, dinv, csr);
    wt_build3_kernel<<<192, 256, 0, stream>>>(W1, W2, W3, wt1, wt2, wt3);

    const int gemmBlocks = (NN / 16 + 3) / 4;  // 6250 waves / 4 per block

    // layer 1 (fp32 input converted in-register)
    gemm_mfma_kernel<true><<<gemmBlocks, 256, 0, stream>>>((const void*)x0, wt1, dinv, hb);
    aggregate_kernel<true><<<NN / 4, 256, 0, stream>>>(hb, csr, cursor, dinv,
                                                       (const float2*)b1, (void*)xact);
    // layer 2
    gemm_mfma_kernel<false><<<gemmBlocks, 256, 0, stream>>>((const void*)xact, wt2, dinv, hb);
    aggregate_kernel<true><<<NN / 4, 256, 0, stream>>>(hb, csr, cursor, dinv,
                                                       (const float2*)b2, (void*)xact);
    // layer 3 -> fp32 final output
    gemm_mfma_kernel<false><<<gemmBlocks, 256, 0, stream>>>((const void*)xact, wt3, dinv, hb);
    aggregate_kernel<false><<<NN / 4, 256, 0, stream>>>(hb, csr, cursor, dinv,
                                                        (const float2*)b3, (void*)out);
}

// Round 9
// 434.744 us; speedup vs baseline: 1.1227x; 1.1227x over previous
//
#include <hip/hip_runtime.h>

#define NN 100000
#define EE 1600000
#define D 128
#define NPART 8                   // dst-space partitions
#define PSZ (NN / NPART)          // 12500 nodes per partition
#define NI4 (EE / 4)              // 400000 int4 records in dst/src
#define SUBW 196                  // dst nodes per sub-bucket (64 per partition)
#define NSB (NPART * 64)          // 512 sub-buckets
#define SCAP 4096                 // records per sub-bucket (exp 3136, +17 sigma)
#define RCAP 8192                 // csr slots per sub-bucket region (exp ~3960)
#define LBCAP 96                  // LDS bin capacity (exp 49, +6.7 sigma; overflow ok)

typedef __attribute__((ext_vector_type(8))) short bf16x8;
typedef __attribute__((ext_vector_type(4))) float f32x4;

// bf16 helpers (exact unpack; RN pack)
__device__ inline unsigned int f2bf2(float a, float b) {  // pack (a=low, b=high)
    unsigned int ua = __float_as_uint(a);
    unsigned int ub = __float_as_uint(b);
    ua = (ua + 0x7fffu + ((ua >> 16) & 1u)) >> 16;
    ub = (ub + 0x7fffu + ((ub >> 16) & 1u)) >> 16;
    return ua | (ub << 16);
}
__device__ inline unsigned short f2bf(float a) {
    unsigned int u = __float_as_uint(a);
    return (unsigned short)((u + 0x7fffu + ((u >> 16) & 1u)) >> 16);
}
__device__ inline float2 bf2f2(unsigned int u) {
    return make_float2(__uint_as_float(u << 16), __uint_as_float(u & 0xffff0000u));
}

// ---------------- graph prep ----------------

// zero sub-bucket cursors + sentinel hs row (index NN)
__global__ void init_kernel(int* __restrict__ gcur2, unsigned int* __restrict__ hb) {
    int i = blockIdx.x * blockDim.x + threadIdx.x;
    if (i < NSB) gcur2[i] = 0;
    if (i < 64) hb[(size_t)NN * 64 + i] = 0;
}

// phase 1: partition-filter + LDS bin into 64 sub-buckets per partition.
// block (p = blk/64, c = blk%64): chunk c of the edge list, keep dst in
// partition p. All global writes are coalesced bin flushes; per-edge atomics
// are LDS-only (overflow falls back to global append — rare, still correct).
__global__ __launch_bounds__(256) void filterbin_kernel(const int4* __restrict__ src4,
                                                        const int4* __restrict__ dst4,
                                                        int* __restrict__ gcur2,
                                                        uint2* __restrict__ buckets2) {
    __shared__ uint2 bins[64][LBCAP];
    __shared__ int bcnt[64];
    __shared__ int gbase[64];
    const int p = blockIdx.x >> 6;
    const int c = blockIdx.x & 63;
    if (threadIdx.x < 64) bcnt[threadIdx.x] = 0;
    __syncthreads();
    const int lo = p * PSZ, hi = lo + PSZ;
    const int chunk4 = NI4 / 64;                    // 6250, exact
    const int a0 = c * chunk4, a1 = a0 + chunk4;
    for (int i = a0 + threadIdx.x; i < a1; i += 256) {
        int4 d4 = dst4[i];
        bool m0 = (d4.x >= lo && d4.x < hi);
        bool m1 = (d4.y >= lo && d4.y < hi);
        bool m2 = (d4.z >= lo && d4.z < hi);
        bool m3 = (d4.w >= lo && d4.w < hi);
        if (!(m0 | m1 | m2 | m3)) continue;
        int4 s4 = src4[i];
        int ss[4] = {s4.x, s4.y, s4.z, s4.w};
        int dd[4] = {d4.x, d4.y, d4.z, d4.w};
        bool mm[4] = {m0, m1, m2, m3};
#pragma unroll
        for (int k = 0; k < 4; ++k) {
            if (!mm[k]) continue;
            int li = (dd[k] - lo) / SUBW;           // 0..63
            int pos = atomicAdd(&bcnt[li], 1);
            if (pos < LBCAP) {
                bins[li][pos] = make_uint2((unsigned)ss[k], (unsigned)dd[k]);
            } else {                                 // rare overflow: direct append
                int sb = p * 64 + li;
                int gp = atomicAdd(&gcur2[sb], 1);
                buckets2[(size_t)sb * SCAP + gp] = make_uint2((unsigned)ss[k], (unsigned)dd[k]);
            }
        }
    }
    __syncthreads();
    if (threadIdx.x < 64) {
        int cc = min(bcnt[threadIdx.x], LBCAP);
        gbase[threadIdx.x] = atomicAdd(&gcur2[p * 64 + threadIdx.x], cc);
        bcnt[threadIdx.x] = cc;
    }
    __syncthreads();
    for (int b = 0; b < 64; ++b) {
        const int cc = bcnt[b];
        uint2* outp = buckets2 + (size_t)(p * 64 + b) * SCAP + gbase[b];
        for (int i = threadIdx.x; i < cc; i += 256) outp[i] = bins[b][i];
    }
}

// phase 2: per sub-bucket LDS counting-sort into padded compact csr rows.
// All per-edge atomics in LDS; global writes are one coalesced int4 stream.
// Emits info[d] = (rowoff<<8)|deg and dinv[d].
__global__ __launch_bounds__(256) void sort3_kernel(const uint2* __restrict__ buckets2,
                                                    const int* __restrict__ gcur2,
                                                    int* __restrict__ csr,
                                                    int* __restrict__ info,
                                                    float* __restrict__ dinv) {
    __shared__ int hist[256];
    __shared__ int pscan[256];
    __shared__ int lcur[256];
    __shared__ int staged[RCAP];
    const int sb = blockIdx.x;
    const int li = sb & 63;
    const int base_node = (sb >> 6) * PSZ + li * SUBW;
    const int nnodes = min(SUBW, PSZ - li * SUBW);  // 196 (152 for last)
    const int scnt = gcur2[sb];
    const uint2* bk = buckets2 + (size_t)sb * SCAP;
    const int t = threadIdx.x;
    hist[t] = 0;
    __syncthreads();
    for (int i = t; i < scnt; i += 256) atomicAdd(&hist[(int)bk[i].y - base_node], 1);
    __syncthreads();
    const int padded = (t < nnodes) ? ((hist[t] + 7) & ~7) : 0;
    pscan[t] = padded;
    __syncthreads();
    for (int off = 1; off < 256; off <<= 1) {
        int v = (t >= off) ? pscan[t - off] : 0;
        __syncthreads();
        pscan[t] += v;
        __syncthreads();
    }
    const int rstart = pscan[t] - padded;           // exclusive scan
    lcur[t] = rstart;
    __syncthreads();
    const int total = pscan[255];                   // multiple of 8
    for (int i = t; i < total; i += 256) staged[i] = NN;  // sentinel fill
    __syncthreads();
    for (int i = t; i < scnt; i += 256) {
        uint2 r = bk[i];
        int pos = atomicAdd(&lcur[(int)r.y - base_node], 1);
        staged[pos] = (int)r.x;
    }
    __syncthreads();
    int4* co = (int4*)(csr + (size_t)sb * RCAP);
    for (int i = t; i < (total >> 2); i += 256) co[i] = ((const int4*)staged)[i];
    if (t < nnodes) {
        int dg = hist[t];
        info[base_node + t] = ((sb * RCAP + rstart) << 8) | dg;   // rowoff<24b, deg<8b
        dinv[base_node + t] = rsqrtf(1.0f + (float)dg);
    }
}

// W[k][n] fp32 -> Wt[n][k] bf16, all three weights in one launch (192 blocks)
__global__ void wt_build3_kernel(const float* __restrict__ W1, const float* __restrict__ W2,
                                 const float* __restrict__ W3, unsigned short* __restrict__ wt1,
                                 unsigned short* __restrict__ wt2, unsigned short* __restrict__ wt3) {
    const int which = blockIdx.x >> 6;
    const float* W = which == 0 ? W1 : (which == 1 ? W2 : W3);
    unsigned short* wt = which == 0 ? wt1 : (which == 1 ? wt2 : wt3);
    int i = (blockIdx.x & 63) * 256 + threadIdx.x;
    int n = i >> 7, k = i & 127;
    wt[n * 128 + k] = f2bf(W[k * 128 + n]);
}

// ---------------- GEMM: hs(bf16) = dinv[row] * (x @ W)  via MFMA ------------
// One wave: 16 rows x 128 cols, K=128 in 4 chunks of 32.
// Operand swap: A = Wt-frag, B = x-frag -> lane holds h[m0+(lane&15)][nt*16+q*4+reg].

template <bool F32IN>
__global__ __launch_bounds__(256) void gemm_mfma_kernel(const void* __restrict__ xin,
                                                        const unsigned short* __restrict__ wt,
                                                        const float* __restrict__ dinv,
                                                        unsigned int* __restrict__ hb) {
    const int wave = blockIdx.x * 4 + (threadIdx.x >> 6);
    const int m0 = wave * 16;
    if (m0 >= NN) return;
    const int lane = threadIdx.x & 63;
    const int r = lane & 15;
    const int q = lane >> 4;
    const unsigned short* wrow = wt + (size_t)r * 128 + q * 8;
    f32x4 acc[8] = {};
#pragma unroll
    for (int kc = 0; kc < 4; ++kc) {
        bf16x8 xf;
        if (F32IN) {
            const float* xrow = (const float*)xin + (size_t)(m0 + r) * 128 + q * 8 + kc * 32;
            float4 a = *(const float4*)xrow;
            float4 b = *(const float4*)(xrow + 4);
            unsigned short tmp[8] = {f2bf(a.x), f2bf(a.y), f2bf(a.z), f2bf(a.w),
                                     f2bf(b.x), f2bf(b.y), f2bf(b.z), f2bf(b.w)};
            xf = *(const bf16x8*)tmp;
        } else {
            const unsigned short* xrow =
                (const unsigned short*)xin + (size_t)(m0 + r) * 128 + q * 8 + kc * 32;
            xf = *(const bf16x8*)xrow;
        }
#pragma unroll
        for (int nt = 0; nt < 8; ++nt) {
            bf16x8 wf = *(const bf16x8*)(wrow + (size_t)nt * 16 * 128 + kc * 32);
            acc[nt] = __builtin_amdgcn_mfma_f32_16x16x32_bf16(wf, xf, acc[nt], 0, 0, 0);
        }
    }
    const float dvr = dinv[m0 + r];
    unsigned int* hrow = hb + (size_t)(m0 + r) * 64;  // uint = 2 bf16
#pragma unroll
    for (int nt = 0; nt < 8; ++nt) {
        int n = nt * 16 + q * 4;
        *(uint2*)(hrow + (n >> 1)) =
            make_uint2(f2bf2(acc[nt][0] * dvr, acc[nt][1] * dvr),
                       f2bf2(acc[nt][2] * dvr, acc[nt][3] * dvr));
    }
}

// ---------------- aggregation: out[d] = relu( dv*(hs[d] + sum_e hs[src_e]) + b )
// 4 waves per block, one node per wave; lane j owns cols 2j,2j+1.
// info[d] = (rowoff<<8)|deg; rows padded to x8 with sentinel NN (zero hs row).

template <bool BF16OUT>
__global__ __launch_bounds__(256) void aggregate_kernel(const unsigned int* __restrict__ hb,
                                                        const int* __restrict__ csr,
                                                        const int* __restrict__ info,
                                                        const float* __restrict__ dinv,
                                                        const float2* __restrict__ bias2,
                                                        void* __restrict__ outp) {
    const int d = blockIdx.x * 4 + (threadIdx.x >> 6);
    const int j = threadIdx.x & 63;     // lane
    const int ifo = info[d];
    int e = ifo >> 8;
    const int end = e + (((ifo & 255) + 7) & ~7);
    float2 acc = bf2f2(hb[(size_t)d * 64 + j]);   // self term: hs[d]
    for (; e + 16 <= end; e += 16) {
        int4 c0 = *(const int4*)(csr + e);
        int4 c1 = *(const int4*)(csr + e + 4);
        int4 c2 = *(const int4*)(csr + e + 8);
        int4 c3 = *(const int4*)(csr + e + 12);
        unsigned int v0 = hb[(size_t)c0.x * 64 + j];
        unsigned int v1 = hb[(size_t)c0.y * 64 + j];
        unsigned int v2 = hb[(size_t)c0.z * 64 + j];
        unsigned int v3 = hb[(size_t)c0.w * 64 + j];
        unsigned int v4 = hb[(size_t)c1.x * 64 + j];
        unsigned int v5 = hb[(size_t)c1.y * 64 + j];
        unsigned int v6 = hb[(size_t)c1.z * 64 + j];
        unsigned int v7 = hb[(size_t)c1.w * 64 + j];
        unsigned int v8 = hb[(size_t)c2.x * 64 + j];
        unsigned int v9 = hb[(size_t)c2.y * 64 + j];
        unsigned int va = hb[(size_t)c2.z * 64 + j];
        unsigned int vb = hb[(size_t)c2.w * 64 + j];
        unsigned int vc = hb[(size_t)c3.x * 64 + j];
        unsigned int vd = hb[(size_t)c3.y * 64 + j];
        unsigned int ve = hb[(size_t)c3.z * 64 + j];
        unsigned int vf = hb[(size_t)c3.w * 64 + j];
        float2 f0 = bf2f2(v0), f1 = bf2f2(v1), f2 = bf2f2(v2), f3 = bf2f2(v3);
        float2 f4 = bf2f2(v4), f5 = bf2f2(v5), f6 = bf2f2(v6), f7 = bf2f2(v7);
        float2 f8 = bf2f2(v8), f9 = bf2f2(v9), fa = bf2f2(va), fb = bf2f2(vb);
        float2 fc = bf2f2(vc), fd = bf2f2(vd), fe = bf2f2(ve), ff = bf2f2(vf);
        acc.x += ((f0.x + f1.x) + (f2.x + f3.x)) + ((f4.x + f5.x) + (f6.x + f7.x)) +
                 ((f8.x + f9.x) + (fa.x + fb.x)) + ((fc.x + fd.x) + (fe.x + ff.x));
        acc.y += ((f0.y + f1.y) + (f2.y + f3.y)) + ((f4.y + f5.y) + (f6.y + f7.y)) +
                 ((f8.y + f9.y) + (fa.y + fb.y)) + ((fc.y + fd.y) + (fe.y + ff.y));
    }
    if (e < end) {  // one trailing 8-batch
        int4 c0 = *(const int4*)(csr + e);
        int4 c1 = *(const int4*)(csr + e + 4);
        unsigned int v0 = hb[(size_t)c0.x * 64 + j];
        unsigned int v1 = hb[(size_t)c0.y * 64 + j];
        unsigned int v2 = hb[(size_t)c0.z * 64 + j];
        unsigned int v3 = hb[(size_t)c0.w * 64 + j];
        unsigned int v4 = hb[(size_t)c1.x * 64 + j];
        unsigned int v5 = hb[(size_t)c1.y * 64 + j];
        unsigned int v6 = hb[(size_t)c1.z * 64 + j];
        unsigned int v7 = hb[(size_t)c1.w * 64 + j];
        float2 f0 = bf2f2(v0), f1 = bf2f2(v1), f2 = bf2f2(v2), f3 = bf2f2(v3);
        float2 f4 = bf2f2(v4), f5 = bf2f2(v5), f6 = bf2f2(v6), f7 = bf2f2(v7);
        acc.x += ((f0.x + f1.x) + (f2.x + f3.x)) + ((f4.x + f5.x) + (f6.x + f7.x));
        acc.y += ((f0.y + f1.y) + (f2.y + f3.y)) + ((f4.y + f5.y) + (f6.y + f7.y));
    }
    const float dv = dinv[d];
    float2 bb = bias2[j];
    float ox = fmaxf(dv * acc.x + bb.x, 0.0f);
    float oy = fmaxf(dv * acc.y + bb.y, 0.0f);
    if (BF16OUT) {
        ((unsigned int*)outp)[(size_t)d * 64 + j] = f2bf2(ox, oy);
    } else {
        ((float2*)outp)[(size_t)d * 64 + j] = make_float2(ox, oy);
    }
}

// ---------------- launch ----------------

extern "C" void kernel_launch(void* const* d_in, const int* in_sizes, int n_in,
                              void* d_out, int out_size, void* d_ws, size_t ws_size,
                              hipStream_t stream) {
    const float* x0 = (const float*)d_in[0];
    const int* ei = (const int*)d_in[1];   // int32 on device (harness contract)
    const float* W1 = (const float*)d_in[2];
    const float* b1 = (const float*)d_in[3];
    const float* W2 = (const float*)d_in[4];
    const float* b2 = (const float*)d_in[5];
    const float* W3 = (const float*)d_in[6];
    const float* b3 = (const float*)d_in[7];
    float* out = (float*)d_out;

    char* ws = (char*)d_ws;
    size_t off = 0;
    auto alloc = [&](size_t bytes) -> void* {
        off = (off + 511) & ~(size_t)511;
        void* p = ws + off;
        off += bytes;
        return p;
    };
    unsigned int* hb  = (unsigned int*)alloc(((size_t)NN + 1) * 64 * 4);   // 25.6 MB hs (+ zero row)
    int*   csr     = (int*)  alloc((size_t)NSB * RCAP * sizeof(int));      // 16.8 MB
    uint2* buckets2 = (uint2*)alloc((size_t)NSB * SCAP * sizeof(uint2));   // 16.8 MB
    int*   info    = (int*)  alloc((size_t)NN * sizeof(int));
    float* dinv    = (float*)alloc((size_t)NN * sizeof(float));
    int*   gcur2   = (int*)  alloc(NSB * sizeof(int));
    unsigned short* wt1 = (unsigned short*)alloc(128 * 128 * 2);
    unsigned short* wt2 = (unsigned short*)alloc(128 * 128 * 2);
    unsigned short* wt3 = (unsigned short*)alloc(128 * 128 * 2);

    // bf16 activation ping buffer for layers 1-2 lives in d_out's first 25.6 MB
    unsigned int* xact = (unsigned int*)d_out;

    const int4* src4 = (const int4*)ei;          // edge_index[0]
    const int4* dst4 = (const int4*)(ei + EE);   // edge_index[1]

    // graph prep (redone every call: ws is re-poisoned)
    init_kernel<<<2, 256, 0, stream>>>(gcur2, hb);
    filterbin_kernel<<<NSB, 256, 0, stream>>>(src4, dst4, gcur2, buckets2);
    sort3_kernel<<<NSB, 256, 0, stream>>>(buckets2, gcur2, csr, info, dinv);
    wt_build3_kernel<<<192, 256, 0, stream>>>(W1, W2, W3, wt1, wt2, wt3);

    const int gemmBlocks = (NN / 16 + 3) / 4;  // 6250 waves / 4 per block

    // layer 1 (fp32 input converted in-register)
    gemm_mfma_kernel<true><<<gemmBlocks, 256, 0, stream>>>((const void*)x0, wt1, dinv, hb);
    aggregate_kernel<true><<<NN / 4, 256, 0, stream>>>(hb, csr, info, dinv,
                                                       (const float2*)b1, (void*)xact);
    // layer 2
    gemm_mfma_kernel<false><<<gemmBlocks, 256, 0, stream>>>((const void*)xact, wt2, dinv, hb);
    aggregate_kernel<true><<<NN / 4, 256, 0, stream>>>(hb, csr, info, dinv,
                                                       (const float2*)b2, (void*)xact);
    // layer 3 -> fp32 final output
    gemm_mfma_kernel<false><<<gemmBlocks, 256, 0, stream>>>((const void*)xact, wt3, dinv, hb);
    aggregate_kernel<false><<<NN / 4, 256, 0, stream>>>(hb, csr, info, dinv,
                                                        (const float2*)b3, (void*)out);
}